// Round 11
// baseline (843.283 us; speedup 1.0000x reference)
//
#include <hip/hip_runtime.h>
#include <math.h>

#define LL 32
#define BB 4
#define DD 64
#define NH 4
#define DKK 16
#define BN_INV 0.9999950000374997f

__device__ __forceinline__ float lrelu(float v){ return v > 0.f ? v : 0.01f*v; }

__device__ __forceinline__ float wave_sum(float v){
  #pragma unroll
  for(int off=1; off<64; off<<=1) v += __shfl_xor(v, off, 64);
  return v;
}

// ---- merged prep: eff (64) | pos (8) | wT (200) | wT3 (18) | w2T (32) | stats-zero (1)
__global__ __launch_bounds__(256) void k_prep(
    const float* __restrict__ c1w, const float* __restrict__ c1b,
    const float* __restrict__ wk,  const float* __restrict__ wv,
    const float* __restrict__ w2,  const float* __restrict__ gw4,
    const float* __restrict__ ffw2,
    float* __restrict__ A, float* __restrict__ bf, float* __restrict__ pos,
    float* __restrict__ wT, float* __restrict__ wT3, float* __restrict__ w2T,
    float* __restrict__ stats){
  int blk = blockIdx.x, t = threadIdx.x;
  if(blk < 64){                                     // ---- eff: A, bf
    int tid = blk*256 + t;
    int k = tid & 15, d = (tid>>4)&63, n=(tid>>10)&3, tt=(tid>>12)&1, i=tid>>13;
    const float* wsel = (tt ? wv : wk) + (i*NH+n)*64*16;
    const float* cw   = c1w + ((i*NH+n)*192 + (tt+1)*64)*64;
    float acc = 0.f;
    for(int c=0;c<64;++c) acc += cw[c*64+d]*wsel[c*16+k];
    A[tid] = acc;
    if(d==0){
      const float* cb = c1b + (i*NH+n)*192 + (tt+1)*64;
      float ba=0.f;
      for(int c=0;c<64;++c) ba += cb[c]*wsel[c*16+k];
      bf[((i*2+tt)*4+n)*16+k] = ba;
    }
  } else if(blk < 72){                              // ---- pos table
    int tid = (blk-64)*256 + t;
    int d = tid & 63, l = tid >> 6;
    float ex = (float)(d>>1) / 32.0f;
    float angle = (float)l * powf(10000.0f, -ex);
    pos[tid] = (l & 1) ? cosf(angle) : sinf(angle);
  } else if(blk < 272){                             // ---- wT (conv2 weights)
    int tid = (blk-72)*256 + t;
    int k = tid & 15; int rest = tid >> 4;
    int tap = rest % 25; int rest2 = rest / 25;
    int c = rest2 & 15; int dn = rest2 >> 4;
    wT[tid] = w2[((dn*16 + k)*16 + c)*25 + tap];
  } else if(blk < 290){                             // ---- wT3 (gw4 transpose), 4608 exact
    int tid = (blk-272)*256 + t;
    int co = tid & 63, ct = tid >> 6;
    wT3[ct*64 + co] = gw4[co*72 + ct];
  } else if(blk < 322){                             // ---- w2T (ff_w2 transpose), 8192 exact
    int tid = (blk-290)*256 + t;
    int l = tid & 31; int m = (tid>>5)&127; int dep = tid>>12;
    w2T[tid] = ffw2[dep*4096 + l*128 + m];
  } else {                                          // ---- zero 4 stats slots (1024 floats)
    #pragma unroll
    for(int j=0;j<4;++j) stats[t + j*256] = 0.f;
  }
}

// ---- fused frontend L1-3: 3->4->6->8 channels, chained zero-padded LDS tiles
__global__ __launch_bounds__(256) void k_front(const float* __restrict__ x,
    const float* __restrict__ gw1, const float* __restrict__ gb1,
    const float* __restrict__ gw2, const float* __restrict__ gb2,
    const float* __restrict__ gw3, const float* __restrict__ gb3,
    float* __restrict__ out8){
  __shared__ float sh[4212];
  float* T0 = sh; float* T1 = sh + 972; float* T2 = sh + 2268;
  int f = blockIdx.x, t = threadIdx.x;
  int h = t>>4, w = t&15;
  for(int j=t;j<4212;j+=256) sh[j]=0.f;
  __syncthreads();
  for(int ci=0;ci<3;++ci) T0[ci*324 + (h+1)*18 + (w+1)] = x[f*768 + ci*256 + t];
  __syncthreads();
  for(int co=0;co<4;++co){
    float acc = gb1[co];
    for(int ci=0;ci<3;++ci){
      const float* tb = T0 + ci*324 + h*18 + w;
      const float* wb = gw1 + co*27 + ci*9;
      #pragma unroll
      for(int dy=0;dy<3;++dy)
        #pragma unroll
        for(int dx=0;dx<3;++dx) acc += tb[dy*18+dx]*wb[dy*3+dx];
    }
    T1[co*324 + (h+1)*18 + (w+1)] = lrelu(acc*BN_INV);
  }
  __syncthreads();
  for(int co=0;co<6;++co){
    float acc = gb2[co];
    for(int ci=0;ci<4;++ci){
      const float* tb = T1 + ci*324 + h*18 + w;
      const float* wb = gw2 + co*36 + ci*9;
      #pragma unroll
      for(int dy=0;dy<3;++dy)
        #pragma unroll
        for(int dx=0;dx<3;++dx) acc += tb[dy*18+dx]*wb[dy*3+dx];
    }
    T2[co*324 + (h+1)*18 + (w+1)] = lrelu(acc*BN_INV);
  }
  __syncthreads();
  for(int co=0;co<8;++co){
    float acc = gb3[co];
    for(int ci=0;ci<6;++ci){
      const float* tb = T2 + ci*324 + h*18 + w;
      const float* wb = gw3 + co*54 + ci*9;
      #pragma unroll
      for(int dy=0;dy<3;++dy)
        #pragma unroll
        for(int dx=0;dx<3;++dx) acc += tb[dy*18+dx]*wb[dy*3+dx];
    }
    out8[f*2048 + co*256 + t] = lrelu(acc*BN_INV);
  }
}

// ---- L4 conv3: 8 -> 64 ch + pos-add + LN1-stats accumulation (slot0)
__global__ __launch_bounds__(256) void k_conv3_l4(const float* __restrict__ in8,
    const float* __restrict__ wT3, const float* __restrict__ gb4,
    const float* __restrict__ pos, float* __restrict__ out,
    float* __restrict__ nst){
  __shared__ float tile[8*324];
  __shared__ float wsl[1152];
  int blk = blockIdx.x; int g = blk & 3; int f = blk >> 2;
  int t = threadIdx.x; int h = t>>4, w = t&15;
  for(int j=t;j<2592;j+=256) tile[j]=0.f;
  for(int j=t;j<1152;j+=256){
    int ct = j>>4, c16 = j&15;
    wsl[j] = wT3[ct*64 + g*16 + c16];
  }
  __syncthreads();
  for(int ci=0;ci<8;++ci) tile[ci*324 + (h+1)*18 + (w+1)] = in8[f*2048 + ci*256 + t];
  __syncthreads();
  float acc[16];
  #pragma unroll
  for(int q=0;q<16;++q) acc[q] = gb4[g*16+q];
  for(int ci=0;ci<8;++ci){
    const float* tb = tile + ci*324 + h*18 + w;
    #pragma unroll
    for(int dy=0;dy<3;++dy){
      #pragma unroll
      for(int dx=0;dx<3;++dx){
        float v = tb[dy*18+dx];
        const float* wp = wsl + (ci*9+dy*3+dx)*16;
        float4 wa = *(const float4*)(wp);
        float4 wb = *(const float4*)(wp+4);
        float4 wc = *(const float4*)(wp+8);
        float4 wd = *(const float4*)(wp+12);
        acc[0]+=v*wa.x; acc[1]+=v*wa.y; acc[2]+=v*wa.z; acc[3]+=v*wa.w;
        acc[4]+=v*wb.x; acc[5]+=v*wb.y; acc[6]+=v*wb.z; acc[7]+=v*wb.w;
        acc[8]+=v*wc.x; acc[9]+=v*wc.y; acc[10]+=v*wc.z; acc[11]+=v*wc.w;
        acc[12]+=v*wd.x; acc[13]+=v*wd.y; acc[14]+=v*wd.z; acc[15]+=v*wd.w;
      }
    }
  }
  int l = f >> 2;
  float s = 0.f, s2 = 0.f;
  #pragma unroll
  for(int q=0;q<16;++q){
    float r = lrelu(acc[q]*BN_INV) + pos[l*64 + g*16 + q];
    out[f*16384 + (g*16+q)*256 + t] = r;
    s += r; s2 += r*r;
  }
  float ws_ = wave_sum(s), ws2 = wave_sum(s2);
  if((t & 63) == 0){
    atomicAdd(&nst[f*2],   ws_);
    atomicAdd(&nst[f*2+1], ws2);
  }
}

// ---- fused K/V projection (inline LN1) + per-head 5x5 conv on K
// block = (frame lb, head n) = 512 blocks; thread = pixel; all 16 k per thread.
__global__ __launch_bounds__(256) void k_kvc5(const float* __restrict__ x,
     const float* __restrict__ lnw, const float* __restrict__ lnb,
     const float* __restrict__ st,
     const float* __restrict__ A, const float* __restrict__ bf,
     const float* __restrict__ wT,
     float* __restrict__ V, float* __restrict__ CK, int dep){
  __shared__ float tile[16*400];                    // 16 k x 20x20, zero border
  int blk = blockIdx.x;                             // lb*4 + n
  int n = blk & 3; int lb = blk >> 2;
  int t = threadIdx.x; int h = t>>4, w = t&15;
  for(int j=t;j<6400;j+=256) tile[j]=0.f;
  float Ssum = st[lb*2], S2 = st[lb*2+1];
  float mu = Ssum*(1.0f/16384.f);
  float ri = rsqrtf(S2*(1.0f/16384.f) - mu*mu + 1e-5f);
  const float* xb  = x   + lb*16384 + t;
  const float* wbp = lnw + t;
  const float* bbp = lnb + t;
  const float* akb = A + ((dep*2+0)*4+n)*1024;
  const float* avb = A + ((dep*2+1)*4+n)*1024;
  float kacc[16], vacc[16];
  #pragma unroll
  for(int q=0;q<16;++q){
    kacc[q] = bf[((dep*2+0)*4+n)*16+q];
    vacc[q] = bf[((dep*2+1)*4+n)*16+q];
  }
  for(int d=0;d<64;++d){
    float yv = (xb[d*256]-mu)*ri*wbp[d*256] + bbp[d*256];
    const float* ak = akb + d*16;
    const float* av = avb + d*16;
    #pragma unroll
    for(int q=0;q<16;++q){ kacc[q] += yv*ak[q]; vacc[q] += yv*av[q]; }
  }
  int l = lb >> 2, b = lb & 3;
  int fh = (b*32+l)*4+n;
  __syncthreads();                                  // zero-fill done everywhere
  #pragma unroll
  for(int q=0;q<16;++q){
    V[fh*4096 + q*256 + t] = vacc[q];
    tile[q*400 + (h+2)*20 + (w+2)] = kacc[q];
  }
  __syncthreads();
  const float* wb = wT + (dep*4+n)*6400;            // [c*25+tap][16]
  float acc[16];
  #pragma unroll
  for(int q=0;q<16;++q) acc[q] = 0.f;
  for(int c=0;c<16;++c){
    const float* tb = tile + c*400 + h*20 + w;
    const float* wc = wb + c*400;
    #pragma unroll
    for(int dy=0;dy<5;++dy){
      #pragma unroll
      for(int dx=0;dx<5;++dx){
        float v = tb[dy*20+dx];
        const float* wp = wc + (dy*5+dx)*16;
        float4 wa = *(const float4*)(wp);
        float4 wbv = *(const float4*)(wp+4);
        float4 wcv = *(const float4*)(wp+8);
        float4 wdv = *(const float4*)(wp+12);
        acc[0]+=v*wa.x;  acc[1]+=v*wa.y;  acc[2]+=v*wa.z;  acc[3]+=v*wa.w;
        acc[4]+=v*wbv.x; acc[5]+=v*wbv.y; acc[6]+=v*wbv.z; acc[7]+=v*wbv.w;
        acc[8]+=v*wcv.x; acc[9]+=v*wcv.y; acc[10]+=v*wcv.z; acc[11]+=v*wcv.w;
        acc[12]+=v*wdv.x; acc[13]+=v*wdv.y; acc[14]+=v*wdv.z; acc[15]+=v*wdv.w;
      }
    }
  }
  float* ob = CK + fh*4096;
  #pragma unroll
  for(int q=0;q<16;++q) ob[q*256+t] = acc[q];
}

// ---- softmax over L (query-independent) + weighted V sum -> vout[b][c][p]
__global__ void k_soft(const float* __restrict__ CK, const float* __restrict__ V,
                       float* __restrict__ vout){
  int idx = blockIdx.x*256 + threadIdx.x;
  int p = idx&255; int k=(idx>>8)&15; int n=(idx>>12)&3; int b=idx>>14;
  int base = (b*128 + n)*4096 + k*256 + p;
  float e[32]; float m = -1e30f;
  for(int l=0;l<32;++l){ float v = CK[base + l*16384]; e[l]=v; m = fmaxf(m,v); }
  float s = 0.f;
  for(int l=0;l<32;++l){ e[l] = expf(e[l]-m); s += e[l]; }
  float inv = 1.f/s, acc = 0.f;
  for(int l=0;l<32;++l) acc += e[l]*V[base + l*16384];
  vout[((b*4+n)*16+k)*256+p] = acc*inv;
}

// ---- w0 projection + broadcast residual over all L + LN2-stats accumulation
__global__ void k_w0res(const float* __restrict__ vout, const float* __restrict__ w0,
                        float* __restrict__ xlb, float* __restrict__ nst, int dep){
  int blk = blockIdx.x; int t = threadIdx.x;
  int p = t; int o = blk & 63; int b = blk >> 6;
  const float* vb = vout + b*64*256 + p;
  const float* wb = w0 + dep*4096 + o;
  float acc = 0.f;
  for(int c=0;c<64;++c) acc += vb[c*256]*wb[c*64];
  for(int l=0;l<32;++l){
    int ix = ((l*4+b)*64+o)*256 + p;
    float xn = xlb[ix] + acc;
    xlb[ix] = xn;
    float s = wave_sum(xn), s2 = wave_sum(xn*xn);
    if((t & 63) == 0){
      atomicAdd(&nst[(l*4+b)*2],   s);
      atomicAdd(&nst[(l*4+b)*2+1], s2);
    }
  }
}

// ---- feed-forward over time with inline LN2 (stats from sums), v6:
// static-indexed tail via (l&3)==w guard; optional next-LN1 stats accumulation.
__global__ __launch_bounds__(256) void k_ff(float* __restrict__ xlb,
                     const float* __restrict__ lnw, const float* __restrict__ lnb,
                     const float* __restrict__ st,
                     const float* __restrict__ w1, const float* __restrict__ b1,
                     const float* __restrict__ w2T, const float* __restrict__ b2,
                     float* __restrict__ nst, int dep){
  __shared__ float pfa[4*2048];
  int t = threadIdx.x;
  int lane = t & 63;
  int w = __builtin_amdgcn_readfirstlane(t >> 6);
  int blk = blockIdx.x;
  int elem = blk*64 + lane;                         // (b,d,p); stride over l = 65536
  int b = blk >> 8;                                 // uniform per block
  int e = elem & 16383;
  float lw  = lnw[e];
  float lbv = lnb[e];
  float xv[32], yv[32];
  #pragma unroll
  for(int l=0;l<32;++l) xv[l] = xlb[elem + l*65536];
  #pragma unroll
  for(int l=0;l<32;++l){
    float mu = st[(l*4+b)*2]*(1.0f/16384.f);
    float vv = st[(l*4+b)*2+1]*(1.0f/16384.f) - mu*mu;
    float ri = rsqrtf(vv + 1e-5f);
    yv[l] = (xv[l]-mu)*ri*lw + lbv;
  }
  float fa[32];
  if(w==0){
    #pragma unroll
    for(int l=0;l<32;++l) fa[l] = b2[dep*32+l];
  } else {
    #pragma unroll
    for(int l=0;l<32;++l) fa[l] = 0.f;
  }
  const float* w1b  = w1  + dep*4096 + w*1024;
  const float* w2Tb = w2T + dep*4096 + w*1024;
  const float* b1b  = b1  + dep*128  + w*32;
  #pragma unroll 4
  for(int mm=0;mm<32;++mm){
    float s0=0.f,s1=0.f,s2=0.f,s3=0.f;
    #pragma unroll
    for(int l=0;l<32;l+=4){
      s0 += yv[l+0]*w1b[mm*32+l+0];
      s1 += yv[l+1]*w1b[mm*32+l+1];
      s2 += yv[l+2]*w1b[mm*32+l+2];
      s3 += yv[l+3]*w1b[mm*32+l+3];
    }
    float s = lrelu(((s0+s1)+(s2+s3)) + b1b[mm]);
    #pragma unroll
    for(int l=0;l<32;++l) fa[l] += s*w2Tb[mm*32+l];
  }
  #pragma unroll
  for(int l=0;l<32;++l) pfa[w*2048 + l*64 + lane] = fa[l];
  __syncthreads();
  #pragma unroll
  for(int l=0;l<32;++l){
    if((l & 3) == w){                               // wave-uniform; xv[l] static
      int pi = l*64 + lane;
      float sum = pfa[pi] + pfa[pi+2048] + pfa[pi+4096] + pfa[pi+6144];
      float xn = xv[l] + sum;
      xlb[blk*64 + lane + l*65536] = xn;
      if(nst){
        float s = wave_sum(xn), s2 = wave_sum(xn*xn);
        if(lane == 0){
          atomicAdd(&nst[(l*4+b)*2],   s);
          atomicAdd(&nst[(l*4+b)*2+1], s2);
        }
      }
    }
  }
}

extern "C" void kernel_launch(void* const* d_in, const int* in_sizes, int n_in,
                              void* d_out, int out_size, void* d_ws, size_t ws_size,
                              hipStream_t stream) {
  const float* x       = (const float*)d_in[0];
  const float* gw1     = (const float*)d_in[1];
  const float* gb1     = (const float*)d_in[2];
  const float* gw2     = (const float*)d_in[3];
  const float* gb2     = (const float*)d_in[4];
  const float* gw3     = (const float*)d_in[5];
  const float* gb3     = (const float*)d_in[6];
  const float* gw4     = (const float*)d_in[7];
  const float* gb4     = (const float*)d_in[8];
  const float* conv1_w = (const float*)d_in[9];
  const float* conv1_b = (const float*)d_in[10];
  const float* conv2_w = (const float*)d_in[11];
  // d_in[12] = conv2_b : cancels in softmax; d_in[13] = wq : dead code
  const float* wk      = (const float*)d_in[14];
  const float* wv      = (const float*)d_in[15];
  const float* w0      = (const float*)d_in[16];
  const float* ln1_w   = (const float*)d_in[17];
  const float* ln1_b   = (const float*)d_in[18];
  const float* ln2_w   = (const float*)d_in[19];
  const float* ln2_b   = (const float*)d_in[20];
  const float* ff_w1   = (const float*)d_in[21];
  const float* ff_b1   = (const float*)d_in[22];
  const float* ff_w2   = (const float*)d_in[23];
  const float* ff_b2   = (const float*)d_in[24];

  float* out = (float*)d_out;
  float* ws  = (float*)d_ws;
  float* CK    = ws;                 // 2,097,152 (also frontend 8-ch intermediate)
  float* V     = ws + 2097152;       // 2,097,152
  float* vout  = ws + 4194304;       // 65,536
  float* A     = ws + 4259840;       // 16,384
  float* bf    = ws + 4276224;       // 256
  float* pos   = ws + 4276480;       // 2,048
  float* wT    = ws + 4278528;       // 51,200
  float* wT3   = ws + 4329728;       // 4,608
  float* w2T   = ws + 4334336;       // 8,192
  float* stats = ws + 4342528;       // 1,024 (4 slots x 128 groups x {S,S2})

  float* st0 = stats;                // LN1 dep0 (from conv3_l4)
  float* st1 = stats + 256;          // LN2 dep0 (from w0res dep0)
  float* st2 = stats + 512;          // LN1 dep1 (from ff dep0)
  float* st3 = stats + 768;          // LN2 dep1 (from w0res dep1)

  k_prep<<<323, 256, 0, stream>>>(conv1_w, conv1_b, wk, wv, conv2_w, gw4, ff_w2,
                                  A, bf, pos, wT, wT3, w2T, stats);

  k_front   <<<128, 256, 0, stream>>>(x, gw1, gb1, gw2, gb2, gw3, gb3, CK);
  k_conv3_l4<<<512, 256, 0, stream>>>(CK, wT3, gb4, pos, out, st0);

  for(int dep=0; dep<2; ++dep){
    float* stA = dep ? st2 : st0;
    float* stB = dep ? st3 : st1;
    float* stC = dep ? nullptr : st2;
    k_kvc5 <<<512,  256, 0, stream>>>(out, ln1_w + dep*16384, ln1_b + dep*16384,
                                      stA, A, bf, wT, V, CK, dep);
    k_soft <<<256,  256, 0, stream>>>(CK, V, vout);
    k_w0res<<<256,  256, 0, stream>>>(vout, w0, out, stB, dep);
    k_ff   <<<1024, 256, 0, stream>>>(out, ln2_w + dep*16384, ln2_b + dep*16384,
                                      stB, ff_w1, ff_b1, w2T, ff_b2, stC, dep);
  }
}

// Round 12
// 310.344 us; speedup vs baseline: 2.7173x; 2.7173x over previous
//
#include <hip/hip_runtime.h>
#include <math.h>

#define LL 32
#define BB 4
#define DD 64
#define NH 4
#define DKK 16
#define BN_INV 0.9999950000374997f

__device__ __forceinline__ float lrelu(float v){ return v > 0.f ? v : 0.01f*v; }

// ---- merged prep: eff (64) | pos (8) | wT (200) | wT3 (18) | w2T (32)
__global__ __launch_bounds__(256) void k_prep(
    const float* __restrict__ c1w, const float* __restrict__ c1b,
    const float* __restrict__ wk,  const float* __restrict__ wv,
    const float* __restrict__ w2,  const float* __restrict__ gw4,
    const float* __restrict__ ffw2,
    float* __restrict__ A, float* __restrict__ bf, float* __restrict__ pos,
    float* __restrict__ wT, float* __restrict__ wT3, float* __restrict__ w2T){
  int blk = blockIdx.x, t = threadIdx.x;
  if(blk < 64){                                     // ---- eff: A, bf
    int tid = blk*256 + t;
    int k = tid & 15, d = (tid>>4)&63, n=(tid>>10)&3, tt=(tid>>12)&1, i=tid>>13;
    const float* wsel = (tt ? wv : wk) + (i*NH+n)*64*16;
    const float* cw   = c1w + ((i*NH+n)*192 + (tt+1)*64)*64;
    float acc = 0.f;
    for(int c=0;c<64;++c) acc += cw[c*64+d]*wsel[c*16+k];
    A[tid] = acc;
    if(d==0){
      const float* cb = c1b + (i*NH+n)*192 + (tt+1)*64;
      float ba=0.f;
      for(int c=0;c<64;++c) ba += cb[c]*wsel[c*16+k];
      bf[((i*2+tt)*4+n)*16+k] = ba;
    }
  } else if(blk < 72){                              // ---- pos table
    int tid = (blk-64)*256 + t;
    int d = tid & 63, l = tid >> 6;
    float ex = (float)(d>>1) / 32.0f;
    float angle = (float)l * powf(10000.0f, -ex);
    pos[tid] = (l & 1) ? cosf(angle) : sinf(angle);
  } else if(blk < 272){                             // ---- wT (conv2 weights)
    int tid = (blk-72)*256 + t;
    int k = tid & 15; int rest = tid >> 4;
    int tap = rest % 25; int rest2 = rest / 25;
    int c = rest2 & 15; int dn = rest2 >> 4;
    wT[tid] = w2[((dn*16 + k)*16 + c)*25 + tap];
  } else if(blk < 290){                             // ---- wT3 (gw4 transpose), 4608 exact
    int tid = (blk-272)*256 + t;
    int co = tid & 63, ct = tid >> 6;
    wT3[ct*64 + co] = gw4[co*72 + ct];
  } else {                                          // ---- w2T (ff_w2 transpose), 8192 exact
    int tid = (blk-290)*256 + t;
    int l = tid & 31; int m = (tid>>5)&127; int dep = tid>>12;
    w2T[tid] = ffw2[dep*4096 + l*128 + m];
  }
}

// ---- fused frontend L1-3: 3->4->6->8 channels, chained zero-padded LDS tiles
__global__ __launch_bounds__(256) void k_front(const float* __restrict__ x,
    const float* __restrict__ gw1, const float* __restrict__ gb1,
    const float* __restrict__ gw2, const float* __restrict__ gb2,
    const float* __restrict__ gw3, const float* __restrict__ gb3,
    float* __restrict__ out8){
  __shared__ float sh[4212];
  float* T0 = sh; float* T1 = sh + 972; float* T2 = sh + 2268;
  int f = blockIdx.x, t = threadIdx.x;
  int h = t>>4, w = t&15;
  for(int j=t;j<4212;j+=256) sh[j]=0.f;
  __syncthreads();
  for(int ci=0;ci<3;++ci) T0[ci*324 + (h+1)*18 + (w+1)] = x[f*768 + ci*256 + t];
  __syncthreads();
  for(int co=0;co<4;++co){
    float acc = gb1[co];
    for(int ci=0;ci<3;++ci){
      const float* tb = T0 + ci*324 + h*18 + w;
      const float* wb = gw1 + co*27 + ci*9;
      #pragma unroll
      for(int dy=0;dy<3;++dy)
        #pragma unroll
        for(int dx=0;dx<3;++dx) acc += tb[dy*18+dx]*wb[dy*3+dx];
    }
    T1[co*324 + (h+1)*18 + (w+1)] = lrelu(acc*BN_INV);
  }
  __syncthreads();
  for(int co=0;co<6;++co){
    float acc = gb2[co];
    for(int ci=0;ci<4;++ci){
      const float* tb = T1 + ci*324 + h*18 + w;
      const float* wb = gw2 + co*36 + ci*9;
      #pragma unroll
      for(int dy=0;dy<3;++dy)
        #pragma unroll
        for(int dx=0;dx<3;++dx) acc += tb[dy*18+dx]*wb[dy*3+dx];
    }
    T2[co*324 + (h+1)*18 + (w+1)] = lrelu(acc*BN_INV);
  }
  __syncthreads();
  for(int co=0;co<8;++co){
    float acc = gb3[co];
    for(int ci=0;ci<6;++ci){
      const float* tb = T2 + ci*324 + h*18 + w;
      const float* wb = gw3 + co*54 + ci*9;
      #pragma unroll
      for(int dy=0;dy<3;++dy)
        #pragma unroll
        for(int dx=0;dx<3;++dx) acc += tb[dy*18+dx]*wb[dy*3+dx];
    }
    out8[f*2048 + co*256 + t] = lrelu(acc*BN_INV);
  }
}

// ---- L4 conv3: 8 -> 64 ch, LDS tile + LDS weights, 16 co per thread, pos-add
__global__ __launch_bounds__(256) void k_conv3_l4(const float* __restrict__ in8,
    const float* __restrict__ wT3, const float* __restrict__ gb4,
    const float* __restrict__ pos, float* __restrict__ out){
  __shared__ float tile[8*324];
  __shared__ float wsl[1152];
  int blk = blockIdx.x; int g = blk & 3; int f = blk >> 2;
  int t = threadIdx.x; int h = t>>4, w = t&15;
  for(int j=t;j<2592;j+=256) tile[j]=0.f;
  for(int j=t;j<1152;j+=256){
    int ct = j>>4, c16 = j&15;
    wsl[j] = wT3[ct*64 + g*16 + c16];
  }
  __syncthreads();
  for(int ci=0;ci<8;++ci) tile[ci*324 + (h+1)*18 + (w+1)] = in8[f*2048 + ci*256 + t];
  __syncthreads();
  float acc[16];
  #pragma unroll
  for(int q=0;q<16;++q) acc[q] = gb4[g*16+q];
  for(int ci=0;ci<8;++ci){
    const float* tb = tile + ci*324 + h*18 + w;
    #pragma unroll
    for(int dy=0;dy<3;++dy){
      #pragma unroll
      for(int dx=0;dx<3;++dx){
        float v = tb[dy*18+dx];
        const float* wp = wsl + (ci*9+dy*3+dx)*16;
        float4 wa = *(const float4*)(wp);
        float4 wb = *(const float4*)(wp+4);
        float4 wc = *(const float4*)(wp+8);
        float4 wd = *(const float4*)(wp+12);
        acc[0]+=v*wa.x; acc[1]+=v*wa.y; acc[2]+=v*wa.z; acc[3]+=v*wa.w;
        acc[4]+=v*wb.x; acc[5]+=v*wb.y; acc[6]+=v*wb.z; acc[7]+=v*wb.w;
        acc[8]+=v*wc.x; acc[9]+=v*wc.y; acc[10]+=v*wc.z; acc[11]+=v*wc.w;
        acc[12]+=v*wd.x; acc[13]+=v*wd.y; acc[14]+=v*wd.z; acc[15]+=v*wd.w;
      }
    }
  }
  int l = f >> 2;
  #pragma unroll
  for(int q=0;q<16;++q){
    float r = lrelu(acc[q]*BN_INV) + pos[l*64 + g*16 + q];
    out[f*16384 + (g*16+q)*256 + t] = r;
  }
}

// ---- per-frame LN stats only: stats[g] = (mu, rinv). 128 blocks x 1024 thr.
__global__ __launch_bounds__(1024) void k_stats(const float* __restrict__ x,
                                                float* __restrict__ stats){
  int g = blockIdx.x, t = threadIdx.x;
  const float4* xb = (const float4*)(x + g*16384);
  float s=0.f, s2=0.f;
  #pragma unroll
  for(int j=0;j<4;++j){
    float4 v = xb[t + j*1024];
    s  += v.x + v.y + v.z + v.w;
    s2 += v.x*v.x + v.y*v.y + v.z*v.z + v.w*v.w;
  }
  __shared__ float ls[1024], ls2[1024];
  ls[t]=s; ls2[t]=s2; __syncthreads();
  for(int off=512;off>0;off>>=1){
    if(t<off){ ls[t]+=ls[t+off]; ls2[t]+=ls2[t+off]; }
    __syncthreads();
  }
  if(t==0){
    float mu  = ls[0]*(1.0f/16384.f);
    float var = ls2[0]*(1.0f/16384.f) - mu*mu;
    stats[g*2]   = mu;
    stats[g*2+1] = rsqrtf(var + 1e-5f);
  }
}

// ---- K/V head projections with inline LN1. block = (frame lb, head n).
__global__ __launch_bounds__(256) void k_kv(const float* __restrict__ x,
                     const float* __restrict__ lnw, const float* __restrict__ lnb,
                     const float* __restrict__ stats,
                     const float* __restrict__ A, const float* __restrict__ bf,
                     float* __restrict__ K, float* __restrict__ V, int dep){
  int blk = blockIdx.x;                             // 512: lb*4 + n
  int n = blk & 3; int lb = blk >> 2;
  int t = threadIdx.x;
  float mu = stats[lb*2], ri = stats[lb*2+1];
  const float* xb  = x   + lb*16384 + t;
  const float* wbp = lnw + t;
  const float* bbp = lnb + t;
  const float* akb = A + ((dep*2+0)*4+n)*1024;
  const float* avb = A + ((dep*2+1)*4+n)*1024;
  float kacc[16], vacc[16];
  #pragma unroll
  for(int q=0;q<16;++q){
    kacc[q] = bf[((dep*2+0)*4+n)*16+q];
    vacc[q] = bf[((dep*2+1)*4+n)*16+q];
  }
  for(int d=0;d<64;++d){
    float yv = (xb[d*256]-mu)*ri*wbp[d*256] + bbp[d*256];
    const float* ak = akb + d*16;
    const float* av = avb + d*16;
    #pragma unroll
    for(int q=0;q<16;++q){ kacc[q] += yv*ak[q]; vacc[q] += yv*av[q]; }
  }
  int l = lb >> 2, b = lb & 3;
  int base = ((b*32+l)*4+n)*4096 + t;
  #pragma unroll
  for(int q=0;q<16;++q){ K[base + q*256] = kacc[q]; V[base + q*256] = vacc[q]; }
}

// ---- per-head 5x5 grouped conv on K, register-blocked, zero-padded LDS tile
__global__ __launch_bounds__(256) void k_conv5(const float* __restrict__ K,
                       const float* __restrict__ wT, float* __restrict__ CK, int dep){
  __shared__ float tile[16*400];
  int blk = blockIdx.x;
  int khalf = blk & 1; int fh = blk >> 1; int n = fh & 3;
  int t = threadIdx.x;
  const float* kb = K + fh*4096;
  for(int j=t;j<6400;j+=256) tile[j]=0.f;
  __syncthreads();
  int h = t>>4, w = t&15;
  for(int c=0;c<16;++c) tile[c*400 + (h+2)*20 + (w+2)] = kb[c*256+t];
  __syncthreads();
  const float* wb = wT + (dep*4+n)*6400 + khalf*8;
  float acc[8] = {0.f,0.f,0.f,0.f,0.f,0.f,0.f,0.f};
  for(int c=0;c<16;++c){
    const float* tb = tile + c*400 + h*20 + w;
    const float* wc = wb + c*400;
    #pragma unroll
    for(int dy=0;dy<5;++dy){
      #pragma unroll
      for(int dx=0;dx<5;++dx){
        float v = tb[dy*20+dx];
        const float* wp = wc + (dy*5+dx)*16;
        float4 wa = *(const float4*)(wp);
        float4 wbv = *(const float4*)(wp+4);
        acc[0]+=v*wa.x; acc[1]+=v*wa.y; acc[2]+=v*wa.z; acc[3]+=v*wa.w;
        acc[4]+=v*wbv.x; acc[5]+=v*wbv.y; acc[6]+=v*wbv.z; acc[7]+=v*wbv.w;
      }
    }
  }
  float* ob = CK + fh*4096 + khalf*8*256;
  #pragma unroll
  for(int q=0;q<8;++q) ob[q*256+t] = acc[q];
}

// ---- softmax over L (query-independent) + weighted V sum -> vout[b][c][p]
__global__ void k_soft(const float* __restrict__ CK, const float* __restrict__ V,
                       float* __restrict__ vout){
  int idx = blockIdx.x*256 + threadIdx.x;
  int p = idx&255; int k=(idx>>8)&15; int n=(idx>>12)&3; int b=idx>>14;
  int base = (b*128 + n)*4096 + k*256 + p;
  float e[32]; float m = -1e30f;
  for(int l=0;l<32;++l){ float v = CK[base + l*16384]; e[l]=v; m = fmaxf(m,v); }
  float s = 0.f;
  for(int l=0;l<32;++l){ e[l] = expf(e[l]-m); s += e[l]; }
  float inv = 1.f/s, acc = 0.f;
  for(int l=0;l<32;++l) acc += e[l]*V[base + l*16384];
  vout[((b*4+n)*16+k)*256+p] = acc*inv;
}

// ---- w0 projection + broadcast residual over all L
__global__ void k_w0res(const float* __restrict__ vout, const float* __restrict__ w0,
                        float* __restrict__ xlb, int dep){
  int idx = blockIdx.x*256 + threadIdx.x;
  int p = idx&255; int o=(idx>>8)&63; int b=idx>>14;
  const float* vb = vout + b*64*256 + p;
  const float* wb = w0 + dep*4096 + o;
  float acc = 0.f;
  for(int c=0;c<64;++c) acc += vb[c*256]*wb[c*64];
  for(int l=0;l<32;++l) xlb[((l*4+b)*64+o)*256 + p] += acc;
}

// ---- feed-forward over time with inline LN2, v7:
// NO xv array (yv computed on the fly); tail reloads xlb (L2-resident, unique
// per-thread ownership, no race). yv[32]+fa[32] only -> no spill.
__global__ __launch_bounds__(256) void k_ff(float* __restrict__ xlb,
                     const float* __restrict__ lnw, const float* __restrict__ lnb,
                     const float* __restrict__ stats,
                     const float* __restrict__ w1, const float* __restrict__ b1,
                     const float* __restrict__ w2T, const float* __restrict__ b2,
                     int dep){
  __shared__ float pfa[4*2048];
  int t = threadIdx.x;
  int lane = t & 63;
  int w = __builtin_amdgcn_readfirstlane(t >> 6);
  int blk = blockIdx.x;
  int elem = blk*64 + lane;                         // (b,d,p); stride over l = 65536
  int b = blk >> 8;                                 // uniform per block
  int e = elem & 16383;
  float lw  = lnw[e];
  float lbv = lnb[e];
  float yv[32];
  #pragma unroll
  for(int l=0;l<32;++l){
    float mu = stats[(l*4+b)*2];
    float ri = stats[(l*4+b)*2+1];
    float xv = xlb[elem + l*65536];
    yv[l] = (xv-mu)*ri*lw + lbv;
  }
  float fa[32];
  if(w==0){
    #pragma unroll
    for(int l=0;l<32;++l) fa[l] = b2[dep*32+l];
  } else {
    #pragma unroll
    for(int l=0;l<32;++l) fa[l] = 0.f;
  }
  const float* w1b  = w1  + dep*4096 + w*1024;
  const float* w2Tb = w2T + dep*4096 + w*1024;
  const float* b1b  = b1  + dep*128  + w*32;
  #pragma unroll 4
  for(int mm=0;mm<32;++mm){
    float s0=0.f,s1=0.f,s2=0.f,s3=0.f;
    #pragma unroll
    for(int l=0;l<32;l+=4){
      s0 += yv[l+0]*w1b[mm*32+l+0];
      s1 += yv[l+1]*w1b[mm*32+l+1];
      s2 += yv[l+2]*w1b[mm*32+l+2];
      s3 += yv[l+3]*w1b[mm*32+l+3];
    }
    float s = lrelu(((s0+s1)+(s2+s3)) + b1b[mm]);
    #pragma unroll
    for(int l=0;l<32;++l) fa[l] += s*w2Tb[mm*32+l];
  }
  #pragma unroll
  for(int l=0;l<32;++l) pfa[w*2048 + l*64 + lane] = fa[l];
  __syncthreads();
  #pragma unroll
  for(int j=0;j<8;++j){
    int pi = t + j*256;                             // l = pi>>6 ; lane2 = pi&63
    float sum = pfa[pi] + pfa[pi+2048] + pfa[pi+4096] + pfa[pi+6144];
    int l = pi >> 6, ln2 = pi & 63;
    int ix = blk*64 + ln2 + l*65536;
    xlb[ix] = xlb[ix] + sum;                        // reload: runtime l only in ADDRESS
  }
}

extern "C" void kernel_launch(void* const* d_in, const int* in_sizes, int n_in,
                              void* d_out, int out_size, void* d_ws, size_t ws_size,
                              hipStream_t stream) {
  const float* x       = (const float*)d_in[0];
  const float* gw1     = (const float*)d_in[1];
  const float* gb1     = (const float*)d_in[2];
  const float* gw2     = (const float*)d_in[3];
  const float* gb2     = (const float*)d_in[4];
  const float* gw3     = (const float*)d_in[5];
  const float* gb3     = (const float*)d_in[6];
  const float* gw4     = (const float*)d_in[7];
  const float* gb4     = (const float*)d_in[8];
  const float* conv1_w = (const float*)d_in[9];
  const float* conv1_b = (const float*)d_in[10];
  const float* conv2_w = (const float*)d_in[11];
  // d_in[12] = conv2_b : cancels in softmax; d_in[13] = wq : dead code
  const float* wk      = (const float*)d_in[14];
  const float* wv      = (const float*)d_in[15];
  const float* w0      = (const float*)d_in[16];
  const float* ln1_w   = (const float*)d_in[17];
  const float* ln1_b   = (const float*)d_in[18];
  const float* ln2_w   = (const float*)d_in[19];
  const float* ln2_b   = (const float*)d_in[20];
  const float* ff_w1   = (const float*)d_in[21];
  const float* ff_b1   = (const float*)d_in[22];
  const float* ff_w2   = (const float*)d_in[23];
  const float* ff_b2   = (const float*)d_in[24];

  float* out = (float*)d_out;
  float* ws  = (float*)d_ws;
  float* K     = ws;                 // 2,097,152 (also frontend 8-ch intermediate)
  float* CK    = ws + 2097152;       // 2,097,152
  float* V     = ws + 4194304;       // 2,097,152
  float* vout  = ws + 6291456;       // 65,536
  float* A     = ws + 6356992;       // 16,384
  float* bf    = ws + 6373376;       // 256
  float* pos   = ws + 6373632;       // 2,048
  float* wT    = ws + 6375680;       // 51,200
  float* wT3   = ws + 6426880;       // 4,608
  float* w2T   = ws + 6431488;       // 8,192
  float* stats = ws + 6439680;       // 256

  k_prep<<<322, 256, 0, stream>>>(conv1_w, conv1_b, wk, wv, conv2_w, gw4, ff_w2,
                                  A, bf, pos, wT, wT3, w2T);

  // frontend: fused 3->4->6->8, then specialized 8->64 with pos-add
  k_front   <<<128, 256, 0, stream>>>(x, gw1, gb1, gw2, gb2, gw3, gb3, K);
  k_conv3_l4<<<512, 256, 0, stream>>>(K, wT3, gb4, pos, out);

  for(int dep=0; dep<2; ++dep){
    k_stats<<<128, 1024, 0, stream>>>(out, stats);
    k_kv   <<<512,  256, 0, stream>>>(out, ln1_w + dep*16384, ln1_b + dep*16384,
                                      stats, A, bf, K, V, dep);
    k_conv5<<<1024, 256, 0, stream>>>(K, wT, CK, dep);
    k_soft <<<256,  256, 0, stream>>>(CK, V, vout);
    k_w0res<<<256,  256, 0, stream>>>(vout, w0, out, dep);
    k_stats<<<128, 1024, 0, stream>>>(out, stats);
    k_ff   <<<1024, 256, 0, stream>>>(out, ln2_w + dep*16384, ln2_b + dep*16384,
                                      stats, ff_w1, ff_b1, w2T, ff_b2, dep);
  }
}